// Round 2
// baseline (253.858 us; speedup 1.0000x reference)
//
#include <hip/hip_runtime.h>

typedef float f32x2 __attribute__((ext_vector_type(2)));
typedef float f32x4 __attribute__((ext_vector_type(4)));

#define NRB      256     // rows per block
#define KC       62      // k per chunk (310 = 5*62, no tail)
#define NCHUNK   5
#define LSTRIDE  64      // LDS floats per row

__device__ __forceinline__ f32x2 leaky2(f32x2 v) {
    return __builtin_elementwise_max(v, v * 0.01f);
}

__global__ __launch_bounds__(256, 2) void gen_mlp_tpr(
    const float* __restrict__ x, const float* __restrict__ data_t,
    const float* __restrict__ W1, const float* __restrict__ b1,
    const float* __restrict__ W2, const float* __restrict__ b2,
    const float* __restrict__ W3, const float* __restrict__ b3,
    float* __restrict__ out)
{
    __shared__ float lds[NRB * LSTRIDE];   // 64 KB -> 2 blocks/CU

    const int t    = threadIdx.x;
    const int r0   = blockIdx.x * NRB;
    const int lane = t & 63;
    const int wv   = t >> 6;
    const int rbase = wv * 2 + (lane >> 5);   // 0..7, unique per (wave,half)
    const int c2    = lane & 31;              // float2 col within chunk
    const bool act  = (c2 < 31);              // 31 float2 = 62 floats per row-chunk

    const f32x2* x2 = (const f32x2*)x;
    const size_t xbase = (size_t)(r0 + rbase) * 155 + c2;  // float2 units

    f32x2 px[32];

    // ---- prologue: stage chunk 0 ----
    #pragma unroll
    for (int i = 0; i < 32; ++i)
        if (act) px[i] = x2[xbase + (size_t)i * 1240];
    #pragma unroll
    for (int i = 0; i < 32; ++i) {
        const int rs  = i * 8 + rbase;
        const int col = (2 * c2) ^ ((rs & 15) << 2);   // XOR swizzle, quad-preserving
        if (act) *(f32x2*)&lds[rs * LSTRIDE + col] = px[i];
    }
    __syncthreads();

    f32x2 acc[5] = {{0.f,0.f},{0.f,0.f},{0.f,0.f},{0.f,0.f},{0.f,0.f}};
    const int myrow  = t;
    const int mymask = (myrow & 15) << 2;
    const int mybase = myrow * LSTRIDE;

    #pragma unroll
    for (int c = 0; c < NCHUNK; ++c) {
        // T14: issue next chunk's global loads before compute (latency hides)
        if (c < NCHUNK - 1) {
            #pragma unroll
            for (int i = 0; i < 32; ++i)
                if (act) px[i] = x2[xbase + (size_t)(c + 1) * 31 + (size_t)i * 1240];
        }
        // ---- L1 partial: 62 k's of my row; W1 via uniform (SGPR) loads ----
        const float* Wc = W1 + c * (KC * 10);
        #pragma unroll
        for (int q = 0; q < 15; ++q) {
            f32x4 xq = *(const f32x4*)&lds[mybase + ((4 * q) ^ mymask)];
            #pragma unroll
            for (int kk = 0; kk < 4; ++kk) {
                const float xs = xq[kk];
                const f32x2 xss = {xs, xs};
                const f32x2* wp = (const f32x2*)(Wc + (4 * q + kk) * 10);
                #pragma unroll
                for (int j = 0; j < 5; ++j)
                    acc[j] += xss * wp[j];        // v_pk_fma_f32
            }
        }
        {   // k = 60, 61
            f32x2 xq = *(const f32x2*)&lds[mybase + (60 ^ mymask)];
            #pragma unroll
            for (int kk = 0; kk < 2; ++kk) {
                const float xs = (kk == 0) ? xq.x : xq.y;
                const f32x2 xss = {xs, xs};
                const f32x2* wp = (const f32x2*)(Wc + (60 + kk) * 10);
                #pragma unroll
                for (int j = 0; j < 5; ++j)
                    acc[j] += xss * wp[j];
            }
        }
        __syncthreads();                      // everyone done reading buffer
        if (c < NCHUNK - 1) {
            #pragma unroll
            for (int i = 0; i < 32; ++i) {
                const int rs  = i * 8 + rbase;
                const int col = (2 * c2) ^ ((rs & 15) << 2);
                if (act) *(f32x2*)&lds[rs * LSTRIDE + col] = px[i];
            }
            __syncthreads();                  // buffer ready for next compute
        }
    }

    // ---- h1 = leaky(acc + b1) ----
    float h1[10];
    #pragma unroll
    for (int j = 0; j < 5; ++j) {
        f32x2 bb = *(const f32x2*)(b1 + 2 * j);
        f32x2 v  = leaky2(acc[j] + bb);
        h1[2 * j]     = v.x;
        h1[2 * j + 1] = v.y;
    }

    // ---- L2 (10->128) + L3 (128->2), all uniform weights, pk math ----
    f32x2 p = {0.f, 0.f};
    #pragma unroll
    for (int jg = 0; jg < 16; ++jg) {
        f32x2 hh[4];
        #pragma unroll
        for (int m = 0; m < 4; ++m)
            hh[m] = *(const f32x2*)(b2 + jg * 8 + 2 * m);
        #pragma unroll
        for (int k = 0; k < 10; ++k) {
            const f32x2 hs = {h1[k], h1[k]};
            const f32x2* w2p = (const f32x2*)(W2 + k * 128 + jg * 8);
            #pragma unroll
            for (int m = 0; m < 4; ++m)
                hh[m] += hs * w2p[m];
        }
        #pragma unroll
        for (int m = 0; m < 4; ++m) {
            f32x2 v = leaky2(hh[m]);
            const int j0 = jg * 8 + 2 * m;
            f32x2 w3a = *(const f32x2*)(W3 + j0 * 2);        // (W3[j0][0], W3[j0][1])
            f32x2 w3b = *(const f32x2*)(W3 + j0 * 2 + 2);
            f32x2 va = {v.x, v.x}, vb = {v.y, v.y};
            p += va * w3a;
            p += vb * w3b;
        }
    }
    {
        f32x2 bb3 = *(const f32x2*)b3;
        p = leaky2(p + bb3);
    }

    // ---- epilogue: stash (c0,c1), then coalesced float4 poly pass ----
    *(f32x2*)&lds[t * 2] = p;     // safe: past the c=4 barrier
    __syncthreads();

    const f32x4* dt4 = (const f32x4*)data_t;
    f32x4* o4 = (f32x4*)out;
    const size_t base4 = (size_t)r0 * 25;     // 100 floats = 25 float4 per row
    #pragma unroll
    for (int i = 0; i < 25; ++i) {
        const int idx  = i * 256 + t;
        const int trow = idx / 25;             // magic-mul division
        f32x2 cc = *(const f32x2*)&lds[trow * 2];
        f32x4 tv = dt4[base4 + idx];
        f32x4 u  = tv * cc.y + cc.x;           // c0 + c1*t
        o4[base4 + idx] = tv * u;              // t*(c0 + c1*t)
    }
}

extern "C" void kernel_launch(void* const* d_in, const int* in_sizes, int n_in,
                              void* d_out, int out_size, void* d_ws, size_t ws_size,
                              hipStream_t stream) {
    const float* x      = (const float*)d_in[0];
    const float* data_t = (const float*)d_in[1];
    const float* W1     = (const float*)d_in[2];
    const float* b1     = (const float*)d_in[3];
    const float* W2     = (const float*)d_in[4];
    const float* b2     = (const float*)d_in[5];
    const float* W3     = (const float*)d_in[6];
    const float* b3     = (const float*)d_in[7];
    float* out = (float*)d_out;

    // 512 blocks x 256 threads = 131072 threads, one row each; 2 blocks/CU
    gen_mlp_tpr<<<512, 256, 0, stream>>>(x, data_t, W1, b1, W2, b2, W3, b3, out);
}

// Round 3
// 98.468 us; speedup vs baseline: 2.5781x; 2.5781x over previous
//
#include <hip/hip_runtime.h>
#include <stdint.h>

typedef float f32x2 __attribute__((ext_vector_type(2)));
typedef float f32x4 __attribute__((ext_vector_type(4)));

#define NROWS 64        // rows per block (one wave)
#define KC    31        // k's per chunk (310 = 10*31)
#define NCH   10
#define LSTR  36        // LDS dwords per row: 144 B = 16B-aligned stride
#define BUFSZ (NROWS * LSTR)   // 2304 floats per chunk buffer

__device__ __forceinline__ f32x2 leaky2(f32x2 v) {
    return __builtin_elementwise_max(v, v * 0.01f);
}

// CK-idiom global->LDS direct copy, 4 bytes per lane (alignment-safe).
__device__ __forceinline__ void gload_dw_lds(const float* g, float* l) {
    auto gp = reinterpret_cast<const float __attribute__((address_space(1)))*>(
        reinterpret_cast<uintptr_t>(g));
    auto lp = reinterpret_cast<float __attribute__((address_space(3)))*>(
        reinterpret_cast<uintptr_t>(l));
    __builtin_amdgcn_global_load_lds(gp, lp, 4, 0, 0);
}

// Stage one chunk: 64 rows x 31 dwords. Call under `if (lane < 31)`.
// src = x + r0*310 + c*31 + klane (per-lane), advances one row per instr.
// LDS dest is wave-uniform; HW adds lane*4 -> row-linear [r][0..30].
__device__ __forceinline__ void stage_chunk(const float* src, float* ldsbuf) {
    #pragma unroll 8
    for (int r = 0; r < NROWS; ++r) {
        gload_dw_lds(src, ldsbuf + r * LSTR);
        src += 310;
    }
}

// Accumulate 31 k's of layer 1 from this thread's LDS row (16B-aligned).
__device__ __forceinline__ void chunk_accum(f32x2* acc, const float* xr,
                                            const float* __restrict__ W) {
    float xk[31];
    *(f32x4*)&xk[0]  = *(const f32x4*)(xr + 0);
    *(f32x4*)&xk[4]  = *(const f32x4*)(xr + 4);
    *(f32x4*)&xk[8]  = *(const f32x4*)(xr + 8);
    *(f32x4*)&xk[12] = *(const f32x4*)(xr + 12);
    *(f32x4*)&xk[16] = *(const f32x4*)(xr + 16);
    *(f32x4*)&xk[20] = *(const f32x4*)(xr + 20);
    *(f32x4*)&xk[24] = *(const f32x4*)(xr + 24);
    *(f32x2*)&xk[28] = *(const f32x2*)(xr + 28);
    xk[30] = xr[30];
    #pragma unroll
    for (int k = 0; k < 31; ++k) {
        const f32x2 xx = {xk[k], xk[k]};
        #pragma unroll
        for (int j = 0; j < 5; ++j)
            acc[j] += xx * (*(const f32x2*)(W + k * 10 + 2 * j)); // v_pk_fma_f32, W from SGPRs
    }
}

__global__ __launch_bounds__(64, 2) void gen_mlp_wave(
    const float* __restrict__ x, const float* __restrict__ data_t,
    const float* __restrict__ W1, const float* __restrict__ b1,
    const float* __restrict__ W2, const float* __restrict__ b2,
    const float* __restrict__ W3, const float* __restrict__ b3,
    float* __restrict__ out)
{
    __shared__ float smem[2 * BUFSZ + 2 * NROWS];   // 18944 B -> 8 blocks/CU

    const int lane = threadIdx.x;            // block = 1 wave
    const int r0   = blockIdx.x * NROWS;
    const int klane = (lane < 31) ? lane : 30;          // masked lanes: safe addr
    const float* srcb = x + (size_t)r0 * 310 + klane;   // per-lane base

    // ---- prologue: stage chunk 0 (async, zero VGPR) ----
    if (lane < 31) stage_chunk(srcb, smem);

    // ---- main loop: issue next chunk, counted wait, compute current ----
    f32x2 acc[5] = {{0.f,0.f},{0.f,0.f},{0.f,0.f},{0.f,0.f},{0.f,0.f}};
    for (int c = 0; c < NCH - 1; ++c) {
        if (lane < 31)
            stage_chunk(srcb + (c + 1) * KC, smem + ((c + 1) & 1) * BUFSZ);
        // all of chunk c (the 64 oldest) retired; <=63 of c+1 stay in flight
        asm volatile("s_waitcnt vmcnt(63)" ::: "memory");
        chunk_accum(acc, smem + (c & 1) * BUFSZ + lane * LSTR, W1 + c * 310);
    }
    asm volatile("s_waitcnt vmcnt(0)" ::: "memory");
    chunk_accum(acc, smem + BUFSZ + lane * LSTR, W1 + 9 * 310);  // chunk 9 -> buf 1

    // ---- h1 = leaky(acc + b1) ----
    float h1[10];
    #pragma unroll
    for (int j = 0; j < 5; ++j) {
        f32x2 bb = *(const f32x2*)(b1 + 2 * j);
        f32x2 v  = leaky2(acc[j] + bb);
        h1[2 * j] = v.x; h1[2 * j + 1] = v.y;
    }

    // ---- L2 (10->128) + L3 (128->2) fused, uniform weights (SGPR) ----
    f32x2 p = {0.f, 0.f};
    #pragma unroll
    for (int jg = 0; jg < 16; ++jg) {
        f32x2 hh[4];
        #pragma unroll
        for (int m = 0; m < 4; ++m)
            hh[m] = *(const f32x2*)(b2 + jg * 8 + 2 * m);
        #pragma unroll
        for (int k = 0; k < 10; ++k) {
            const f32x2 hs = {h1[k], h1[k]};
            const f32x2* w2p = (const f32x2*)(W2 + k * 128 + jg * 8);
            #pragma unroll
            for (int m = 0; m < 4; ++m)
                hh[m] += hs * w2p[m];
        }
        #pragma unroll
        for (int m = 0; m < 4; ++m) {
            f32x2 v = leaky2(hh[m]);
            const int j0 = jg * 8 + 2 * m;
            f32x2 w3a = *(const f32x2*)(W3 + j0 * 2);
            f32x2 w3b = *(const f32x2*)(W3 + j0 * 2 + 2);
            p += (f32x2){v.x, v.x} * w3a;
            p += (f32x2){v.y, v.y} * w3b;
        }
    }
    p = leaky2(p + *(const f32x2*)b3);

    // ---- stash coeffs, then block-local coalesced poly pass ----
    f32x2* cst = (f32x2*)(smem + 2 * BUFSZ);
    cst[lane] = p;
    __syncthreads();

    const f32x4* dt4 = (const f32x4*)data_t + (size_t)r0 * 25;  // 100 f = 25 f32x4/row
    f32x4*       o4  = (f32x4*)out        + (size_t)r0 * 25;
    #pragma unroll
    for (int i = 0; i < 25; ++i) {
        const int idx = i * 64 + lane;       // 0..1599, coalesced
        const int row = idx / 25;            // 0..63 (magic-mul)
        f32x2 cc = cst[row];
        f32x4 tv = dt4[idx];
        f32x4 u  = tv * cc.y + cc.x;         // c0 + c1*t
        o4[idx]  = tv * u;                   // t*(c0 + c1*t)
    }
}

extern "C" void kernel_launch(void* const* d_in, const int* in_sizes, int n_in,
                              void* d_out, int out_size, void* d_ws, size_t ws_size,
                              hipStream_t stream) {
    const float* x      = (const float*)d_in[0];
    const float* data_t = (const float*)d_in[1];
    const float* W1     = (const float*)d_in[2];
    const float* b1     = (const float*)d_in[3];
    const float* W2     = (const float*)d_in[4];
    const float* b2     = (const float*)d_in[5];
    const float* W3     = (const float*)d_in[6];
    const float* b3     = (const float*)d_in[7];
    float* out = (float*)d_out;

    // 2048 blocks x 1 wave x 64 rows = 131072 rows, one pass, 8 blocks/CU
    gen_mlp_wave<<<2048, 64, 0, stream>>>(x, data_t, W1, b1, W2, b2, W3, b3, out);
}